// Round 2
// baseline (322.897 us; speedup 1.0000x reference)
//
#include <hip/hip_runtime.h>
#include <math.h>
#include <stdint.h>

// MoE: B=8192 tokens, D_IN=1024, 8 experts, D_EXP=1024, top-2.
// Pipeline: gate_cast (gating+x-cast | w2 transpose | rowTok init)
// -> slot kernel (block 0 = slot assign @256-row granularity, rest = w1 transpose)
// -> moe_gemm<GATHER,GELU> x2: 256x256 deep-pipelined bf16 MFMA GEMM
//    (counted vmcnt(8), raw barriers, setprio, XOR-swizzled LDS)
// -> weighted combine.

#define NTOK   8192
#define DIN    1024
#define NEXP   8
#define DEXP   1024
#define MAXROWS 18432   // 16384 assignments + per-expert pad to 256 (72*256)
#define MAXT   72       // max 256-row tiles

typedef __bf16 bf16x8_t __attribute__((ext_vector_type(8)));
typedef float f32x4 __attribute__((ext_vector_type(4)));

__device__ __forceinline__ unsigned short f2bf(float f) {
  union { float f; unsigned int u; } v; v.f = f;
  unsigned int u = v.u;
  u += 0x7fffu + ((u >> 16) & 1u);   // round-to-nearest-even
  return (unsigned short)(u >> 16);
}

__device__ __forceinline__ float bf2f(unsigned short s) {
  union { unsigned int u; float f; } v; v.u = ((unsigned int)s) << 16;
  return v.f;
}

__device__ __forceinline__ void async16(const void* g, void* l) {
  __builtin_amdgcn_global_load_lds((const __attribute__((address_space(1))) void*)g,
                                   (__attribute__((address_space(3))) void*)l, 16, 0, 0);
}

// fast GELU: tanh form via sigmoid, max abs err ~3e-4 (threshold is 5.7e-2)
__device__ __forceinline__ float gelu_fast(float v) {
  float u = v * (1.5957691216057308f + 0.07135481627f * v * v);
  return v * (1.0f / (1.0f + __expf(-u)));
}

// ---------------- gate+cast: [0,2048) gating | [2048,4096) w2 transpose | [4096,4114) rowTok init
__global__ __launch_bounds__(256) void gate_cast_kernel(const float* __restrict__ x,
                                                        const float* __restrict__ gw,
                                                        const float* __restrict__ w2,
                                                        unsigned short* __restrict__ xbf,
                                                        unsigned short* __restrict__ w2T,
                                                        float* __restrict__ outGate,
                                                        int* __restrict__ topE,
                                                        float* __restrict__ topW,
                                                        int* __restrict__ rowTok) {
  __shared__ __align__(16) char smem[32768];
  int b = blockIdx.x;
  int tid = threadIdx.x;
  if (b >= 4096) {
    // ---- rowTok = -1 (18 blocks x 1024 ints)
    int base = (b - 4096) * 1024 + tid * 4;
    *(int4*)(rowTok + base) = make_int4(-1, -1, -1, -1);
    return;
  }
  if (b >= 2048) {
    // ---- w2 transpose+cast: [e][k][n] fp32 -> [e][n][k] bf16, 64x64 tile
    float* tile = (float*)smem;             // 64*65*4 = 16.6KB
    int idx = b - 2048;
    int e = idx >> 8, rest = idx & 255, kt = rest >> 4, nt = rest & 15;
    const float* s = w2 + (size_t)e * DEXP * DEXP + (size_t)kt * 64 * 1024 + nt * 64;
    unsigned short* d = w2T + (size_t)e * DEXP * DEXP + (size_t)nt * 64 * 1024 + kt * 64;
    int a = tid & 15, r0 = tid >> 4;
    #pragma unroll
    for (int p = 0; p < 4; ++p) {
      int r = r0 + p * 16;
      float4 v = *(const float4*)(s + (size_t)r * 1024 + a * 4);
      tile[r * 65 + a * 4 + 0] = v.x;
      tile[r * 65 + a * 4 + 1] = v.y;
      tile[r * 65 + a * 4 + 2] = v.z;
      tile[r * 65 + a * 4 + 3] = v.w;
    }
    __syncthreads();
    #pragma unroll
    for (int p = 0; p < 4; ++p) {
      int nr = r0 + p * 16;
      ushort4 o;
      o.x = f2bf(tile[(a * 4 + 0) * 65 + nr]);
      o.y = f2bf(tile[(a * 4 + 1) * 65 + nr]);
      o.z = f2bf(tile[(a * 4 + 2) * 65 + nr]);
      o.w = f2bf(tile[(a * 4 + 3) * 65 + nr]);
      *(ushort4*)(d + (size_t)nr * 1024 + a * 4) = o;
    }
    return;
  }
  // ---- gating + x cast: gw staged transposed in LDS, one token per wave
  float (*gwT)[1024] = (float(*)[1024])smem;   // 32KB
  #pragma unroll
  for (int it = 0; it < 8; ++it) {
    int idx = it * 256 + tid;         // 0..2047 float4 chunks of gw[1024][8]
    int fk = idx >> 1;
    int e0 = (idx & 1) * 4;
    float4 g = *(const float4*)(gw + fk * 8 + e0);
    gwT[e0 + 0][fk] = g.x; gwT[e0 + 1][fk] = g.y;
    gwT[e0 + 2][fk] = g.z; gwT[e0 + 3][fk] = g.w;
  }
  __syncthreads();

  int lane = tid & 63, wv = tid >> 6;
  int t = b * 4 + wv;
  const float4* xr = (const float4*)(x + (size_t)t * 1024);
  ushort4* xo = (ushort4*)(xbf + (size_t)t * 1024);
  double acc[NEXP];
  #pragma unroll
  for (int e = 0; e < NEXP; ++e) acc[e] = 0.0;
  #pragma unroll
  for (int j = 0; j < 4; ++j) {
    int q = lane + 64 * j;
    float4 v = xr[q];
    ushort4 r;
    r.x = f2bf(v.x); r.y = f2bf(v.y); r.z = f2bf(v.z); r.w = f2bf(v.w);
    xo[q] = r;
    float vv[4] = {v.x, v.y, v.z, v.w};
    #pragma unroll
    for (int e = 0; e < NEXP; ++e) {
      float4 g = *(const float4*)&gwT[e][4 * q];
      acc[e] += (double)vv[0] * (double)g.x;
      acc[e] += (double)vv[1] * (double)g.y;
      acc[e] += (double)vv[2] * (double)g.z;
      acc[e] += (double)vv[3] * (double)g.w;
    }
  }
  #pragma unroll
  for (int off = 32; off > 0; off >>= 1) {
    #pragma unroll
    for (int e = 0; e < NEXP; ++e) acc[e] += __shfl_xor(acc[e], off);
  }
  if (lane == 0) {
    int e0 = 0; double v0 = acc[0];
    #pragma unroll
    for (int e = 1; e < NEXP; ++e) if (acc[e] > v0) { v0 = acc[e]; e0 = e; }
    int e1 = -1; double v1 = -1e300;
    #pragma unroll
    for (int e = 0; e < NEXP; ++e) if (e != e0 && acc[e] > v1) { v1 = acc[e]; e1 = e; }
    float ex = expf((float)(v1 - v0));
    float inv = 1.0f / (1.0f + ex);
    float w0 = inv, w1v = ex * inv;
    float g8[8];
    #pragma unroll
    for (int e = 0; e < NEXP; ++e) g8[e] = 0.f;
    g8[e0] = w0; g8[e1] = w1v;
    float4* gp = (float4*)(outGate + t * 8);
    gp[0] = *(float4*)&g8[0];
    gp[1] = *(float4*)&g8[4];
    topE[t * 2 + 0] = e0; topE[t * 2 + 1] = e1;
    topW[t * 2 + 0] = w0; topW[t * 2 + 1] = w1v;
  }
}

// ---------------- slot assign (block 0, 256-row tiles) + w1 transpose ----------
__global__ __launch_bounds__(1024) void slot_kernel(const int* __restrict__ topE,
                                                    int* __restrict__ topRow,
                                                    int* __restrict__ rowTok,
                                                    int* __restrict__ tileExpert,
                                                    int* __restrict__ tileRowBase,
                                                    const float* __restrict__ w1,
                                                    unsigned short* __restrict__ w1T) {
  __shared__ int wtot[16][NEXP];
  __shared__ int wbase[16][NEXP];
  __shared__ int soff[NEXP];
  __shared__ float tile[64 * 65];
  int tid = threadIdx.x;
  if (blockIdx.x != 0) {
    // ---- w1 transpose+cast, 1024 threads, one f4 in / one us4 out per thread
    int idx = blockIdx.x - 1;               // 0..2047
    int e = idx >> 8, rest = idx & 255, kt = rest >> 4, nt = rest & 15;
    const float* s = w1 + (size_t)e * DIN * DEXP + (size_t)kt * 64 * 1024 + nt * 64;
    unsigned short* d = w1T + (size_t)e * DIN * DEXP + (size_t)nt * 64 * 1024 + kt * 64;
    int a = tid & 15, r = tid >> 4;
    float4 v = *(const float4*)(s + (size_t)r * 1024 + a * 4);
    tile[r * 65 + a * 4 + 0] = v.x;
    tile[r * 65 + a * 4 + 1] = v.y;
    tile[r * 65 + a * 4 + 2] = v.z;
    tile[r * 65 + a * 4 + 3] = v.w;
    __syncthreads();
    int nr = r;
    ushort4 o;
    o.x = f2bf(tile[(a * 4 + 0) * 65 + nr]);
    o.y = f2bf(tile[(a * 4 + 1) * 65 + nr]);
    o.z = f2bf(tile[(a * 4 + 2) * 65 + nr]);
    o.w = f2bf(tile[(a * 4 + 3) * 65 + nr]);
    *(ushort4*)(d + (size_t)nr * 1024 + a * 4) = o;
    return;
  }
  int lane = tid & 63, wv = tid >> 6;
  int a0 = tid * 16;
  unsigned long long pk = 0ull;
  int cnt[NEXP];
  #pragma unroll
  for (int e = 0; e < NEXP; ++e) cnt[e] = 0;
  for (int i = 0; i < 16; ++i) {
    int e = topE[a0 + i];
    pk |= (unsigned long long)e << (i * 4);
    cnt[e]++;
  }
  int excl[NEXP];
  #pragma unroll
  for (int e = 0; e < NEXP; ++e) {
    int v = cnt[e], sum = v;
    #pragma unroll
    for (int d = 1; d < 64; d <<= 1) {
      int u = __shfl_up(sum, d);
      if (lane >= d) sum += u;
    }
    excl[e] = sum - v;
    if (lane == 63) wtot[wv][e] = sum;
  }
  __syncthreads();
  if (tid == 0) {
    int counts[NEXP];
    for (int e = 0; e < NEXP; ++e) {
      int s = 0;
      for (int w = 0; w < 16; ++w) { wbase[w][e] = s; s += wtot[w][e]; }
      counts[e] = s;
    }
    int row = 0, tl = 0;
    for (int e = 0; e < NEXP; ++e) {
      soff[e] = row;
      int nt = (counts[e] + 255) >> 8;      // 256-row tiles
      for (int i = 0; i < nt; ++i) { tileExpert[tl] = e; tileRowBase[tl] = row + i * 256; ++tl; }
      row += nt << 8;
    }
    for (; tl < MAXT; ++tl) tileExpert[tl] = -1;
  }
  __syncthreads();
  int base[NEXP], run[NEXP];
  #pragma unroll
  for (int e = 0; e < NEXP; ++e) { base[e] = soff[e] + wbase[wv][e] + excl[e]; run[e] = 0; }
  for (int i = 0; i < 16; ++i) {
    int e = (int)((pk >> (i * 4)) & 7ull);
    int row = base[e] + run[e]++;
    rowTok[row] = (a0 + i) >> 1;
    topRow[a0 + i] = row;
  }
}

// ---------------- 256x256 deep-pipelined MoE GEMM ----------------
// 512 threads = 8 waves (2M x 4N), per-wave 128x64 output, BK=64, NT=16.
// LDS 128KB: A buf0 [0,32K) buf1 [32K,64K); B buf0 [64K,96K) buf1 [96K,128K).
// K-loop: 4 phases x {ds_read frags; s_barrier; setprio; 16 MFMA; setprio; s_barrier}.
// Boundary: stage tile t+2 into freed buffer, s_waitcnt vmcnt(8) (= tile t+1
// landed, t+2 stays in flight across the next 4 phases), s_barrier.
template <bool GATHER, bool GELU>
__global__ __launch_bounds__(512, 2) void moe_gemm_kernel(
    const unsigned short* __restrict__ Asrc,   // xbf (gather) or h (linear)
    const unsigned short* __restrict__ Wt,     // w1T or w2T  [e][n][k] bf16
    const float* __restrict__ bias,            // b1 or b2
    const int* __restrict__ tileExpert,
    const int* __restrict__ tileRowBase,
    const int* __restrict__ rowTok,
    unsigned short* __restrict__ Out) {
  int e = tileExpert[blockIdx.x];
  if (e < 0) return;
  int rowBase = tileRowBase[blockIdx.x];
  int n0 = blockIdx.y * 256;
  __shared__ __align__(16) unsigned short sm[65536];   // 128 KB

  int tid = threadIdx.x;
  int lane = tid & 63, wq = tid >> 6;        // wave 0..7
  int wr = wq >> 2, wc = wq & 3;             // 2M x 4N wave grid
  int rsel = lane & 15, qq = (lane >> 4) & 3, rk = rsel & 7;
  int sid = tid >> 3, sch = tid & 7;         // staging row-in-64 / 16B chunk
  int swz8 = (sch ^ (sid & 7)) * 8;          // XOR-swizzled k-chunk (shorts)

  int arow[4];
  #pragma unroll
  for (int j = 0; j < 4; ++j) {
    int r = rowBase + j * 64 + sid;
    if (GATHER) { int tk = rowTok[r]; arow[j] = tk < 0 ? 0 : tk; }
    else arow[j] = r;
  }
  const unsigned short* Bsrc = Wt + (size_t)e * 1024 * 1024;

  auto stage = [&](int T) {
    int kk_ = T * 64;
    int sel_ = (T & 1) * 32768;
    #pragma unroll
    for (int j = 0; j < 4; ++j) {
      int ab = __builtin_amdgcn_readfirstlane(sel_ + j * 8192 + wq * 1024);
      async16(Asrc + (size_t)arow[j] * 1024 + kk_ + swz8, (char*)sm + ab);
      async16(Bsrc + (size_t)(n0 + j * 64 + sid) * 1024 + kk_ + swz8,
              (char*)sm + 65536 + ab);
    }
  };

  f32x4 acc[8][4] = {};

  // prologue: tiles 0 and 1 in flight; wait tile 0 (8 of 16 loads retired)
  stage(0);
  stage(1);
  asm volatile("s_waitcnt vmcnt(8)" ::: "memory");
  __builtin_amdgcn_s_barrier();

  for (int t = 0; t < 16; ++t) {
    int sel = (t & 1) * 32768;
    const unsigned short* sA = (const unsigned short*)((const char*)sm + sel);
    const unsigned short* sB = (const unsigned short*)((const char*)sm + 65536 + sel);
    // B fragments: same 4 n-frags used by all 4 phases of this tile
    bf16x8_t bfr[4][2];
    #pragma unroll
    for (int ni = 0; ni < 4; ++ni)
      #pragma unroll
      for (int ks = 0; ks < 2; ++ks)
        bfr[ni][ks] = *(const bf16x8_t*)
            &sB[(wc * 64 + ni * 16 + rsel) * 64 + ((qq + 4 * ks) ^ rk) * 8];
    #pragma unroll
    for (int p = 0; p < 4; ++p) {
      bf16x8_t af[2][2];
      #pragma unroll
      for (int d = 0; d < 2; ++d)
        #pragma unroll
        for (int ks = 0; ks < 2; ++ks)
          af[d][ks] = *(const bf16x8_t*)
              &sA[(wr * 128 + (p * 2 + d) * 16 + rsel) * 64 + ((qq + 4 * ks) ^ rk) * 8];
      __builtin_amdgcn_s_barrier();
      __builtin_amdgcn_s_setprio(1);
      #pragma unroll
      for (int d = 0; d < 2; ++d)
        #pragma unroll
        for (int ni = 0; ni < 4; ++ni)
          #pragma unroll
          for (int ks = 0; ks < 2; ++ks)
            acc[p * 2 + d][ni] = __builtin_amdgcn_mfma_f32_16x16x32_bf16(
                af[d][ks], bfr[ni][ks], acc[p * 2 + d][ni], 0, 0, 0);
      __builtin_amdgcn_s_setprio(0);
      __builtin_amdgcn_s_barrier();
    }
    // boundary: refill freed buffer with tile t+2, ensure tile t+1 landed
    if (t + 2 < 16) {
      stage(t + 2);
      asm volatile("s_waitcnt vmcnt(8)" ::: "memory");
    } else {
      asm volatile("s_waitcnt vmcnt(0)" ::: "memory");
    }
    __builtin_amdgcn_s_barrier();
  }

  // epilogue: bias (+gelu) -> bf16 -> LDS (256x256) -> coalesced store
  __syncthreads();
  float bv[4];
  #pragma unroll
  for (int ni = 0; ni < 4; ++ni)
    bv[ni] = bias[e * 1024 + n0 + wc * 64 + ni * 16 + rsel];
  #pragma unroll
  for (int mi = 0; mi < 8; ++mi)
    #pragma unroll
    for (int ni = 0; ni < 4; ++ni)
      #pragma unroll
      for (int r = 0; r < 4; ++r) {
        int m = wr * 128 + mi * 16 + qq * 4 + r;
        int n = wc * 64 + ni * 16 + rsel;
        float v = acc[mi][ni][r] + bv[ni];
        if (GELU) v = gelu_fast(v);
        sm[m * 256 + n] = f2bf(v);
      }
  __syncthreads();
  #pragma unroll
  for (int i = 0; i < 16; ++i) {
    int idx = i * 8192 + tid * 16;          // byte offset in 128KB
    int m = idx >> 9, cb = idx & 511;       // 512B per row
    *(uint4*)(Out + (size_t)(rowBase + m) * 1024 + n0 + (cb >> 1)) =
        *(const uint4*)((const char*)sm + idx);
  }
}

// ---------------- combine: out[t] = w0*y[r0] + w1*y[r1] ----------------
__global__ __launch_bounds__(256) void combine_kernel(const unsigned short* __restrict__ y,
                                                      const int* __restrict__ topRow,
                                                      const float* __restrict__ topW,
                                                      float* __restrict__ out) {
  int tid = threadIdx.x;
  int wv = tid >> 6, lane = tid & 63;
  int t = blockIdx.x * 4 + wv;
  int r0 = topRow[t * 2 + 0], r1 = topRow[t * 2 + 1];
  float w0 = topW[t * 2 + 0], w1 = topW[t * 2 + 1];
  const unsigned short* p0 = y + (size_t)r0 * 1024 + lane * 16;
  const unsigned short* p1 = y + (size_t)r1 * 1024 + lane * 16;
  float* op = out + (size_t)t * 1024 + lane * 16;
  #pragma unroll
  for (int hh = 0; hh < 2; ++hh) {
    union { uint4 v; unsigned short s[8]; } a, b;
    a.v = *(const uint4*)(p0 + hh * 8);
    b.v = *(const uint4*)(p1 + hh * 8);
    float o[8];
    #pragma unroll
    for (int j = 0; j < 8; ++j)
      o[j] = w0 * bf2f(a.s[j]) + w1 * bf2f(b.s[j]);
    *(float4*)(op + hh * 8) = *(float4*)&o[0];
    *(float4*)(op + hh * 8 + 4) = *(float4*)&o[4];
  }
}

extern "C" void kernel_launch(void* const* d_in, const int* in_sizes, int n_in,
                              void* d_out, int out_size, void* d_ws, size_t ws_size,
                              hipStream_t stream) {
  const float* x  = (const float*)d_in[0];
  const float* gw = (const float*)d_in[1];
  const float* w1 = (const float*)d_in[2];
  const float* b1 = (const float*)d_in[3];
  const float* w2 = (const float*)d_in[4];
  const float* b2 = (const float*)d_in[5];
  float* out = (float*)d_out;

  char* ws = (char*)d_ws;
  int* tileExpert  = (int*)ws;                            // 72
  int* tileRowBase = tileExpert + MAXT;                   // 72
  int* topE        = tileRowBase + MAXT;                  // 16384
  int* topRow      = topE + 16384;                        // 16384
  float* topW      = (float*)(topRow + 16384);            // 16384
  int* rowTok      = (int*)(ws + (256 << 10));            // 18432 ints
  unsigned short* xbf  = (unsigned short*)(ws + (512 << 10));
  unsigned short* w1T  = xbf + (size_t)NTOK * DIN;
  unsigned short* w2T  = w1T + (size_t)NEXP * DIN * DEXP;
  unsigned short* hbuf = w2T + (size_t)NEXP * DEXP * DEXP;
  unsigned short* ybuf = hbuf + (size_t)MAXROWS * DEXP;

  gate_cast_kernel<<<2048 + 2048 + 18, 256, 0, stream>>>(x, gw, w2, xbf, w2T,
                                                         out + (size_t)NTOK * DEXP,
                                                         topE, topW, rowTok);
  slot_kernel<<<1 + 2048, 1024, 0, stream>>>(topE, topRow, rowTok, tileExpert,
                                             tileRowBase, w1, w1T);
  moe_gemm_kernel<true, true><<<dim3(MAXT, 4), 512, 0, stream>>>(
      xbf, w1T, b1, tileExpert, tileRowBase, rowTok, hbuf);
  moe_gemm_kernel<false, false><<<dim3(MAXT, 4), 512, 0, stream>>>(
      hbuf, w2T, b2, tileExpert, tileRowBase, rowTok, ybuf);
  combine_kernel<<<NTOK / 4, 256, 0, stream>>>(ybuf, topRow, topW, out);
}

// Round 3
// 296.583 us; speedup vs baseline: 1.0887x; 1.0887x over previous
//
#include <hip/hip_runtime.h>
#include <math.h>
#include <stdint.h>

// MoE: B=8192 tokens, D_IN=1024, 8 experts, D_EXP=1024, top-2.
// Pipeline: gate_cast (gating+x-cast | w2 transpose | rowTok init)
// -> slot kernel (block 0 = slot assign, 128-row tiles; rest = w1 transpose)
// -> moe_gemm<GATHER,GELU> x2: 128x128 BK=32 double-buffered bf16 MFMA GEMM,
//    counted vmcnt(4) (no drain), 32KB LDS -> 4-5 independent blocks/CU,
//    grid (pan=8, tile): pan == XCD under round-robin -> B panel L2-resident
// -> weighted combine.

#define NTOK   8192
#define DIN    1024
#define NEXP   8
#define DEXP   1024
#define MAXROWS 18432   // 16384 assignments + per-expert pad to 256
#define MAXT   144      // max 128-row tiles (rows padded to 256 per expert)

typedef __bf16 bf16x8_t __attribute__((ext_vector_type(8)));
typedef float f32x4 __attribute__((ext_vector_type(4)));

__device__ __forceinline__ unsigned short f2bf(float f) {
  union { float f; unsigned int u; } v; v.f = f;
  unsigned int u = v.u;
  u += 0x7fffu + ((u >> 16) & 1u);   // round-to-nearest-even
  return (unsigned short)(u >> 16);
}

__device__ __forceinline__ float bf2f(unsigned short s) {
  union { unsigned int u; float f; } v; v.u = ((unsigned int)s) << 16;
  return v.f;
}

__device__ __forceinline__ void async16(const void* g, void* l) {
  __builtin_amdgcn_global_load_lds((const __attribute__((address_space(1))) void*)g,
                                   (__attribute__((address_space(3))) void*)l, 16, 0, 0);
}

// fast GELU: tanh form via sigmoid, max abs err ~3e-4 (threshold is 5.7e-2)
__device__ __forceinline__ float gelu_fast(float v) {
  float u = v * (1.5957691216057308f + 0.07135481627f * v * v);
  return v * (1.0f / (1.0f + __expf(-u)));
}

// ---------------- gate+cast: [0,2048) gating | [2048,4096) w2 transpose | [4096,4114) rowTok init
__global__ __launch_bounds__(256) void gate_cast_kernel(const float* __restrict__ x,
                                                        const float* __restrict__ gw,
                                                        const float* __restrict__ w2,
                                                        unsigned short* __restrict__ xbf,
                                                        unsigned short* __restrict__ w2T,
                                                        float* __restrict__ outGate,
                                                        int* __restrict__ topE,
                                                        float* __restrict__ topW,
                                                        int* __restrict__ rowTok) {
  __shared__ __align__(16) char smem[32768];
  int b = blockIdx.x;
  int tid = threadIdx.x;
  if (b >= 4096) {
    // ---- rowTok = -1 (18 blocks x 1024 ints)
    int base = (b - 4096) * 1024 + tid * 4;
    *(int4*)(rowTok + base) = make_int4(-1, -1, -1, -1);
    return;
  }
  if (b >= 2048) {
    // ---- w2 transpose+cast: [e][k][n] fp32 -> [e][n][k] bf16, 64x64 tile
    float* tile = (float*)smem;             // 64*65*4 = 16.6KB
    int idx = b - 2048;
    int e = idx >> 8, rest = idx & 255, kt = rest >> 4, nt = rest & 15;
    const float* s = w2 + (size_t)e * DEXP * DEXP + (size_t)kt * 64 * 1024 + nt * 64;
    unsigned short* d = w2T + (size_t)e * DEXP * DEXP + (size_t)nt * 64 * 1024 + kt * 64;
    int a = tid & 15, r0 = tid >> 4;
    #pragma unroll
    for (int p = 0; p < 4; ++p) {
      int r = r0 + p * 16;
      float4 v = *(const float4*)(s + (size_t)r * 1024 + a * 4);
      tile[r * 65 + a * 4 + 0] = v.x;
      tile[r * 65 + a * 4 + 1] = v.y;
      tile[r * 65 + a * 4 + 2] = v.z;
      tile[r * 65 + a * 4 + 3] = v.w;
    }
    __syncthreads();
    #pragma unroll
    for (int p = 0; p < 4; ++p) {
      int nr = r0 + p * 16;
      ushort4 o;
      o.x = f2bf(tile[(a * 4 + 0) * 65 + nr]);
      o.y = f2bf(tile[(a * 4 + 1) * 65 + nr]);
      o.z = f2bf(tile[(a * 4 + 2) * 65 + nr]);
      o.w = f2bf(tile[(a * 4 + 3) * 65 + nr]);
      *(ushort4*)(d + (size_t)nr * 1024 + a * 4) = o;
    }
    return;
  }
  // ---- gating + x cast: gw staged transposed in LDS, one token per wave
  float (*gwT)[1024] = (float(*)[1024])smem;   // 32KB
  #pragma unroll
  for (int it = 0; it < 8; ++it) {
    int idx = it * 256 + tid;         // 0..2047 float4 chunks of gw[1024][8]
    int fk = idx >> 1;
    int e0 = (idx & 1) * 4;
    float4 g = *(const float4*)(gw + fk * 8 + e0);
    gwT[e0 + 0][fk] = g.x; gwT[e0 + 1][fk] = g.y;
    gwT[e0 + 2][fk] = g.z; gwT[e0 + 3][fk] = g.w;
  }
  __syncthreads();

  int lane = tid & 63, wv = tid >> 6;
  int t = b * 4 + wv;
  const float4* xr = (const float4*)(x + (size_t)t * 1024);
  ushort4* xo = (ushort4*)(xbf + (size_t)t * 1024);
  double acc[NEXP];
  #pragma unroll
  for (int e = 0; e < NEXP; ++e) acc[e] = 0.0;
  #pragma unroll
  for (int j = 0; j < 4; ++j) {
    int q = lane + 64 * j;
    float4 v = xr[q];
    ushort4 r;
    r.x = f2bf(v.x); r.y = f2bf(v.y); r.z = f2bf(v.z); r.w = f2bf(v.w);
    xo[q] = r;
    float vv[4] = {v.x, v.y, v.z, v.w};
    #pragma unroll
    for (int e = 0; e < NEXP; ++e) {
      float4 g = *(const float4*)&gwT[e][4 * q];
      acc[e] += (double)vv[0] * (double)g.x;
      acc[e] += (double)vv[1] * (double)g.y;
      acc[e] += (double)vv[2] * (double)g.z;
      acc[e] += (double)vv[3] * (double)g.w;
    }
  }
  #pragma unroll
  for (int off = 32; off > 0; off >>= 1) {
    #pragma unroll
    for (int e = 0; e < NEXP; ++e) acc[e] += __shfl_xor(acc[e], off);
  }
  if (lane == 0) {
    int e0 = 0; double v0 = acc[0];
    #pragma unroll
    for (int e = 1; e < NEXP; ++e) if (acc[e] > v0) { v0 = acc[e]; e0 = e; }
    int e1 = -1; double v1 = -1e300;
    #pragma unroll
    for (int e = 0; e < NEXP; ++e) if (e != e0 && acc[e] > v1) { v1 = acc[e]; e1 = e; }
    float ex = expf((float)(v1 - v0));
    float inv = 1.0f / (1.0f + ex);
    float w0 = inv, w1v = ex * inv;
    float g8[8];
    #pragma unroll
    for (int e = 0; e < NEXP; ++e) g8[e] = 0.f;
    g8[e0] = w0; g8[e1] = w1v;
    float4* gp = (float4*)(outGate + t * 8);
    gp[0] = *(float4*)&g8[0];
    gp[1] = *(float4*)&g8[4];
    topE[t * 2 + 0] = e0; topE[t * 2 + 1] = e1;
    topW[t * 2 + 0] = w0; topW[t * 2 + 1] = w1v;
  }
}

// ---------------- slot assign (block 0, 128-row tiles) + w1 transpose ----------
__global__ __launch_bounds__(1024) void slot_kernel(const int* __restrict__ topE,
                                                    int* __restrict__ topRow,
                                                    int* __restrict__ rowTok,
                                                    int* __restrict__ tileExpert,
                                                    int* __restrict__ tileRowBase,
                                                    const float* __restrict__ w1,
                                                    unsigned short* __restrict__ w1T) {
  __shared__ int wtot[16][NEXP];
  __shared__ int wbase[16][NEXP];
  __shared__ int soff[NEXP];
  __shared__ float tile[64 * 65];
  int tid = threadIdx.x;
  if (blockIdx.x != 0) {
    // ---- w1 transpose+cast, 1024 threads, one f4 in / one us4 out per thread
    int idx = blockIdx.x - 1;               // 0..2047
    int e = idx >> 8, rest = idx & 255, kt = rest >> 4, nt = rest & 15;
    const float* s = w1 + (size_t)e * DIN * DEXP + (size_t)kt * 64 * 1024 + nt * 64;
    unsigned short* d = w1T + (size_t)e * DIN * DEXP + (size_t)nt * 64 * 1024 + kt * 64;
    int a = tid & 15, r = tid >> 4;
    float4 v = *(const float4*)(s + (size_t)r * 1024 + a * 4);
    tile[r * 65 + a * 4 + 0] = v.x;
    tile[r * 65 + a * 4 + 1] = v.y;
    tile[r * 65 + a * 4 + 2] = v.z;
    tile[r * 65 + a * 4 + 3] = v.w;
    __syncthreads();
    int nr = r;
    ushort4 o;
    o.x = f2bf(tile[(a * 4 + 0) * 65 + nr]);
    o.y = f2bf(tile[(a * 4 + 1) * 65 + nr]);
    o.z = f2bf(tile[(a * 4 + 2) * 65 + nr]);
    o.w = f2bf(tile[(a * 4 + 3) * 65 + nr]);
    *(ushort4*)(d + (size_t)nr * 1024 + a * 4) = o;
    return;
  }
  int lane = tid & 63, wv = tid >> 6;
  int a0 = tid * 16;
  unsigned long long pk = 0ull;
  int cnt[NEXP];
  #pragma unroll
  for (int e = 0; e < NEXP; ++e) cnt[e] = 0;
  for (int i = 0; i < 16; ++i) {
    int e = topE[a0 + i];
    pk |= (unsigned long long)e << (i * 4);
    cnt[e]++;
  }
  int excl[NEXP];
  #pragma unroll
  for (int e = 0; e < NEXP; ++e) {
    int v = cnt[e], sum = v;
    #pragma unroll
    for (int d = 1; d < 64; d <<= 1) {
      int u = __shfl_up(sum, d);
      if (lane >= d) sum += u;
    }
    excl[e] = sum - v;
    if (lane == 63) wtot[wv][e] = sum;
  }
  __syncthreads();
  if (tid == 0) {
    int counts[NEXP];
    for (int e = 0; e < NEXP; ++e) {
      int s = 0;
      for (int w = 0; w < 16; ++w) { wbase[w][e] = s; s += wtot[w][e]; }
      counts[e] = s;
    }
    int row = 0, tl = 0;
    for (int e = 0; e < NEXP; ++e) {
      soff[e] = row;
      int nt256 = (counts[e] + 255) >> 8;   // pad rows to 256
      for (int i = 0; i < nt256 * 2; ++i) { // emit 128-row tiles
        tileExpert[tl] = e; tileRowBase[tl] = row + i * 128; ++tl;
      }
      row += nt256 << 8;
    }
    for (; tl < MAXT; ++tl) tileExpert[tl] = -1;
  }
  __syncthreads();
  int base[NEXP], run[NEXP];
  #pragma unroll
  for (int e = 0; e < NEXP; ++e) { base[e] = soff[e] + wbase[wv][e] + excl[e]; run[e] = 0; }
  for (int i = 0; i < 16; ++i) {
    int e = (int)((pk >> (i * 4)) & 7ull);
    int row = base[e] + run[e]++;
    rowTok[row] = (a0 + i) >> 1;
    topRow[a0 + i] = row;
  }
}

// ---------------- 128x128 BK=32 double-buffered MoE GEMM ----------------
// 256 threads = 4 waves (2M x 2N), per-wave 64x64 output. LDS 32KB (2 bufs x
// (A 8KB | B 8KB)) -> 4-5 independent blocks/CU: inter-block overlap hides
// vmcnt/barrier stalls. Counted vmcnt(4): next tile's loads stay in flight,
// no drain in main loop. grid (8, MAXT): blockIdx.x = n-panel = XCD under
// round-robin -> each XCD's B working set = 8 experts x 256KB = 2MB (L2-fit).
template <bool GATHER, bool GELU>
__global__ __launch_bounds__(256, 4) void moe_gemm_kernel(
    const unsigned short* __restrict__ Asrc,   // xbf (gather) or h (linear)
    const unsigned short* __restrict__ Wt,     // w1T or w2T  [e][n][k] bf16
    const float* __restrict__ bias,            // b1 or b2
    const int* __restrict__ tileExpert,
    const int* __restrict__ tileRowBase,
    const int* __restrict__ rowTok,
    unsigned short* __restrict__ Out) {
  int e = tileExpert[blockIdx.y];
  if (e < 0) return;
  int rowBase = tileRowBase[blockIdx.y];
  int n0 = blockIdx.x * 128;
  __shared__ __align__(16) unsigned short sm[16384];   // 32 KB

  int tid = threadIdx.x;
  int lane = tid & 63, wv = tid >> 6;
  int wr = wv >> 1, wc = wv & 1;             // 2M x 2N wave grid
  int rsel = lane & 15, q = (lane >> 4) & 3, rk = rsel & 3;
  int sr = tid >> 2;                         // staging row-in-64
  int swz = ((tid & 3) ^ (sr & 3)) * 8;      // XOR-swizzled 16B k-chunk (shorts)

  int arow[2];
  #pragma unroll
  for (int j = 0; j < 2; ++j) {
    int r = rowBase + j * 64 + sr;
    if (GATHER) { int tk = rowTok[r]; arow[j] = tk < 0 ? 0 : tk; }
    else arow[j] = r;
  }
  const unsigned short* Bsrc = Wt + (size_t)e * 1024 * 1024;

  auto stage = [&](int T) {
    int kk = T * 32;
    int selB = (T & 1) * 16384;              // byte offset of buffer
    #pragma unroll
    for (int j = 0; j < 2; ++j) {
      int ab = __builtin_amdgcn_readfirstlane(selB + j * 4096 + wv * 1024);
      async16(Asrc + (size_t)arow[j] * 1024 + kk + swz, (char*)sm + ab);
      async16(Bsrc + (size_t)(n0 + j * 64 + sr) * 1024 + kk + swz,
              (char*)sm + ab + 8192);
    }
  };

  f32x4 acc[4][4] = {};

  // prologue: tiles 0,1 in flight (8 loads); wait tile 0 (4 retired)
  stage(0);
  stage(1);
  asm volatile("s_waitcnt vmcnt(4)" ::: "memory");
  __builtin_amdgcn_s_barrier();

  for (int t = 0; t < 32; ++t) {
    const unsigned short* sA = sm + (t & 1) * 8192;
    const unsigned short* sB = sA + 4096;
    bf16x8_t af[4], bf[4];
    #pragma unroll
    for (int mi = 0; mi < 4; ++mi)
      af[mi] = *(const bf16x8_t*)&sA[(wr * 64 + mi * 16 + rsel) * 32 + (q ^ rk) * 8];
    #pragma unroll
    for (int ni = 0; ni < 4; ++ni)
      bf[ni] = *(const bf16x8_t*)&sB[(wc * 64 + ni * 16 + rsel) * 32 + (q ^ rk) * 8];
    __builtin_amdgcn_s_setprio(1);
    #pragma unroll
    for (int mi = 0; mi < 4; ++mi)
      #pragma unroll
      for (int ni = 0; ni < 4; ++ni)
        acc[mi][ni] = __builtin_amdgcn_mfma_f32_16x16x32_bf16(af[mi], bf[ni], acc[mi][ni], 0, 0, 0);
    __builtin_amdgcn_s_setprio(0);
    __builtin_amdgcn_s_barrier();            // all waves done reading buf (t&1)
    if (t + 2 < 32) {
      stage(t + 2);                          // refill freed buffer
      asm volatile("s_waitcnt vmcnt(4)" ::: "memory");  // tile t+1 landed
    } else {
      asm volatile("s_waitcnt vmcnt(0)" ::: "memory");
    }
    __builtin_amdgcn_s_barrier();            // buf (t+1)&1 valid for all
  }

  // epilogue: bias (+gelu) -> bf16 -> LDS (128x128) -> coalesced store
  float bv[4];
  int quad = lane >> 4;
  #pragma unroll
  for (int ni = 0; ni < 4; ++ni)
    bv[ni] = bias[e * 1024 + n0 + wc * 64 + ni * 16 + rsel];
  #pragma unroll
  for (int mi = 0; mi < 4; ++mi)
    #pragma unroll
    for (int ni = 0; ni < 4; ++ni)
      #pragma unroll
      for (int r = 0; r < 4; ++r) {
        int m = wr * 64 + mi * 16 + quad * 4 + r;
        int n = wc * 64 + ni * 16 + rsel;
        float v = acc[mi][ni][r] + bv[ni];
        if (GELU) v = gelu_fast(v);
        sm[m * 128 + n] = f2bf(v);
      }
  __syncthreads();
  #pragma unroll
  for (int i = 0; i < 8; ++i) {
    int idx = i * 4096 + tid * 16;           // byte offset in 32KB
    int m = idx >> 8, cb = idx & 255;        // 256B per row
    *(uint4*)(Out + (size_t)(rowBase + m) * 1024 + n0 + (cb >> 1)) =
        *(const uint4*)((const char*)sm + idx);
  }
}

// ---------------- combine: out[t] = w0*y[r0] + w1*y[r1] ----------------
__global__ __launch_bounds__(256) void combine_kernel(const unsigned short* __restrict__ y,
                                                      const int* __restrict__ topRow,
                                                      const float* __restrict__ topW,
                                                      float* __restrict__ out) {
  int tid = threadIdx.x;
  int wv = tid >> 6, lane = tid & 63;
  int t = blockIdx.x * 4 + wv;
  int r0 = topRow[t * 2 + 0], r1 = topRow[t * 2 + 1];
  float w0 = topW[t * 2 + 0], w1 = topW[t * 2 + 1];
  const unsigned short* p0 = y + (size_t)r0 * 1024 + lane * 16;
  const unsigned short* p1 = y + (size_t)r1 * 1024 + lane * 16;
  float* op = out + (size_t)t * 1024 + lane * 16;
  #pragma unroll
  for (int hh = 0; hh < 2; ++hh) {
    union { uint4 v; unsigned short s[8]; } a, b;
    a.v = *(const uint4*)(p0 + hh * 8);
    b.v = *(const uint4*)(p1 + hh * 8);
    float o[8];
    #pragma unroll
    for (int j = 0; j < 8; ++j)
      o[j] = w0 * bf2f(a.s[j]) + w1 * bf2f(b.s[j]);
    *(float4*)(op + hh * 8) = *(float4*)&o[0];
    *(float4*)(op + hh * 8 + 4) = *(float4*)&o[4];
  }
}

extern "C" void kernel_launch(void* const* d_in, const int* in_sizes, int n_in,
                              void* d_out, int out_size, void* d_ws, size_t ws_size,
                              hipStream_t stream) {
  const float* x  = (const float*)d_in[0];
  const float* gw = (const float*)d_in[1];
  const float* w1 = (const float*)d_in[2];
  const float* b1 = (const float*)d_in[3];
  const float* w2 = (const float*)d_in[4];
  const float* b2 = (const float*)d_in[5];
  float* out = (float*)d_out;

  char* ws = (char*)d_ws;
  int* tileExpert  = (int*)ws;                            // 144
  int* tileRowBase = tileExpert + MAXT;                   // 144
  int* topE        = tileRowBase + MAXT;                  // 16384
  int* topRow      = topE + 16384;                        // 16384
  float* topW      = (float*)(topRow + 16384);            // 16384
  int* rowTok      = (int*)(ws + (256 << 10));            // 18432 ints
  unsigned short* xbf  = (unsigned short*)(ws + (512 << 10));
  unsigned short* w1T  = xbf + (size_t)NTOK * DIN;
  unsigned short* w2T  = w1T + (size_t)NEXP * DIN * DEXP;
  unsigned short* hbuf = w2T + (size_t)NEXP * DEXP * DEXP;
  unsigned short* ybuf = hbuf + (size_t)MAXROWS * DEXP;

  gate_cast_kernel<<<2048 + 2048 + 18, 256, 0, stream>>>(x, gw, w2, xbf, w2T,
                                                         out + (size_t)NTOK * DEXP,
                                                         topE, topW, rowTok);
  slot_kernel<<<1 + 2048, 1024, 0, stream>>>(topE, topRow, rowTok, tileExpert,
                                             tileRowBase, w1, w1T);
  moe_gemm_kernel<true, true><<<dim3(8, MAXT), 256, 0, stream>>>(
      xbf, w1T, b1, tileExpert, tileRowBase, rowTok, hbuf);
  moe_gemm_kernel<false, false><<<dim3(8, MAXT), 256, 0, stream>>>(
      hbuf, w2T, b2, tileExpert, tileRowBase, rowTok, ybuf);
  combine_kernel<<<NTOK / 4, 256, 0, stream>>>(ybuf, topRow, topW, out);
}